// Round 2
// baseline (209.368 us; speedup 1.0000x reference)
//
#include <hip/hip_runtime.h>

// CalWeight: out[b,j] = phi[b,j] - phi[b,(j+1)%N]
//   phi[b,j] = atan2(verts_y[b,j] - row[b], verts_x[b,j] - col[b])
// x layout per row: [col, row, v0x, v0y, ... v1023x, v1023y], stride 2050 floats.
//
// R2 = ABLATION PROBE (R1's -50%-VALU change was a perfect null; the kernel's
// own dispatch is absent from the top-5 counter table, i.e. kernel < 78 us
// while dur_us = 205 us -> timed graph is mostly harness poison fills).
// Grid is doubled: odd blocks replay the same row (loads + atan2 + LDS) but
// sink the result via asm volatile instead of storing. Adjacent pairing
// (2b, 2b+1) makes duplicate reads dedup in L2/L3 -> ~zero extra HBM traffic.
// => dur delta vs R1 ~= the kernel's NON-MEMORY cost per pass, and the
// doubled kernel should surface into the top-5 with its own counters.

#define NVERT 1024
#define ROWSTRIDE (2 + 2 * NVERT)
#define BLK 256

__device__ __forceinline__ float fast_atan2f(float dy, float dx) {
    const float ax = __builtin_fabsf(dx);
    const float ay = __builtin_fabsf(dy);
    const float mx = fmaxf(ax, ay);
    const float mn = fminf(ax, ay);
    float t = mn * __builtin_amdgcn_rcpf(mx);
    t = (mx == 0.0f) ? 0.0f : t;  // atan2(0,0) -> 0, keep NaN out
    const float s = t * t;
    float u =                  0.00282363896258175373077393f;
    u = __builtin_fmaf(u, s, -0.0159569028764963150024414f);
    u = __builtin_fmaf(u, s,  0.0425049886107444763183594f);
    u = __builtin_fmaf(u, s, -0.0748900920152664184570312f);
    u = __builtin_fmaf(u, s,  0.106347933411598205566406f);
    u = __builtin_fmaf(u, s, -0.142027363181114196777344f);
    u = __builtin_fmaf(u, s,  0.199926957488059997558594f);
    u = __builtin_fmaf(u, s, -0.333331018686294555664062f);
    float r = __builtin_fmaf(s * u, t, t);            // atan(t), r in [0, pi/4]
    r = (ay > ax) ? (1.5707963267948966f - r) : r;
    r = (dx < 0.0f) ? (3.1415926535897931f - r) : r;
    return __builtin_copysignf(r, dy);
}

__global__ __launch_bounds__(BLK) void calweight_kernel(const float* __restrict__ x,
                                                        float* __restrict__ out) {
    const int b = blockIdx.x >> 1;        // row index (each row done by 2 blocks)
    const int dup = blockIdx.x & 1;       // odd blocks: probe replay, no store
    const int t = threadIdx.x;

    const float* __restrict__ xr = x + (size_t)b * ROWSTRIDE;
    const float colv = xr[0];
    const float rowv = xr[1];

    __shared__ float phi[NVERT];

    // Phase 1: coalesced float2 loads (one vertex per load), compute phi.
    const float2* __restrict__ verts = (const float2*)(xr + 2);
#pragma unroll
    for (int k = 0; k < NVERT / BLK; ++k) {
        const int j = t + k * BLK;
        const float2 v = verts[j];
        phi[j] = fast_atan2f(v.y - rowv, v.x - colv);
    }
    __syncthreads();

    // Phase 2: each thread produces 4 consecutive outputs.
    const int j0 = 4 * t;
    const float4 p = ((const float4*)phi)[t];
    const float pn = phi[(j0 + 4) & (NVERT - 1)];  // wrap: j=1023 -> phi[0]
    float4 r;
    r.x = p.x - p.y;
    r.y = p.y - p.z;
    r.z = p.z - p.w;
    r.w = p.w - pn;

    // Keep the full pipeline live in duplicate blocks (prevents the compiler
    // from sinking loads/atan2 under the store predicate and DCE'ing them).
    asm volatile("" :: "v"(r.x), "v"(r.y), "v"(r.z), "v"(r.w));

    if (!dup) {
        float* __restrict__ orow = out + (size_t)b * NVERT;
        ((float4*)orow)[t] = r;
    }
}

extern "C" void kernel_launch(void* const* d_in, const int* in_sizes, int n_in,
                              void* d_out, int out_size, void* d_ws, size_t ws_size,
                              hipStream_t stream) {
    const float* x = (const float*)d_in[0];
    float* out = (float*)d_out;
    const int B = in_sizes[0] / ROWSTRIDE;  // 16384
    calweight_kernel<<<2 * B, BLK, 0, stream>>>(x, out);
}

// Round 3
// 206.721 us; speedup vs baseline: 1.0128x; 1.0128x over previous
//
#include <hip/hip_runtime.h>

// CalWeight: out[b,j] = phi[b,j] - phi[b,(j+1)%N]
//   phi[b,j] = atan2(verts_y[b,j] - row[b], verts_x[b,j] - col[b])
// x layout per row: [col, row, v0x, v0y, ... v1023x, v1023y], stride 2050 floats.
//
// R3: 16B-aligned read path. R2's ablation proved non-memory cost ~4 us and
// kernel ~40 us vs a 32 us HBM floor (134 MB in + 67 MB out @ 6.29 TB/s).
// Remaining lever: reads were float2 (8 B/lane); the 6.29 TB/s ceiling was
// measured with float4. Single rows are alternately 8-mod-16 misaligned
// (stride 2050 floats), but a ROW PAIR is 16400 B = 1025 x 16 B and pair
// bases are 16B-aligned. One block per pair: load 1025 aligned float4s
// (4/thread + 1 tail), decode header/vertex structure in registers,
// phi -> LDS[2048], float4-diff epilogue stores both rows (output pair is
// one contiguous aligned 8 KB span).

#define NVERT 1024
#define ROWSTRIDE (2 + 2 * NVERT)    // 2050 floats
#define PAIRSTRIDE (2 * ROWSTRIDE)   // 4100 floats = 16400 B (16B-aligned)
#define BLK 256

__device__ __forceinline__ float fast_atan2f(float dy, float dx) {
    const float ax = __builtin_fabsf(dx);
    const float ay = __builtin_fabsf(dy);
    const float mx = fmaxf(ax, ay);
    const float mn = fminf(ax, ay);
    float t = mn * __builtin_amdgcn_rcpf(mx);
    t = (mx == 0.0f) ? 0.0f : t;  // atan2(0,0) -> 0, keep NaN out
    const float s = t * t;
    float u =                  0.00282363896258175373077393f;
    u = __builtin_fmaf(u, s, -0.0159569028764963150024414f);
    u = __builtin_fmaf(u, s,  0.0425049886107444763183594f);
    u = __builtin_fmaf(u, s, -0.0748900920152664184570312f);
    u = __builtin_fmaf(u, s,  0.106347933411598205566406f);
    u = __builtin_fmaf(u, s, -0.142027363181114196777344f);
    u = __builtin_fmaf(u, s,  0.199926957488059997558594f);
    u = __builtin_fmaf(u, s, -0.333331018686294555664062f);
    float r = __builtin_fmaf(s * u, t, t);            // atan(t), r in [0, pi/4]
    r = (ay > ax) ? (1.5707963267948966f - r) : r;
    r = (dx < 0.0f) ? (3.1415926535897931f - r) : r;
    return __builtin_copysignf(r, dy);
}

__global__ __launch_bounds__(BLK) void calweight_kernel(const float* __restrict__ x,
                                                        float* __restrict__ out) {
    const int pb = blockIdx.x;   // row-pair index
    const int t = threadIdx.x;

    const float* __restrict__ xp = x + (size_t)pb * PAIRSTRIDE;
    // Block-uniform headers -> scalar loads (same cache lines as vector loads).
    const float c0 = xp[0], r0 = xp[1];
    const float c1 = xp[ROWSTRIDE], r1 = xp[ROWSTRIDE + 1];

    __shared__ float phi[2 * NVERT];  // [row0 0..1023 | row1 0..1023]

    const float4* __restrict__ vp = (const float4*)xp;  // 16B-aligned

    // float4 q covers floats 4q..4q+3 of the pair region:
    //   q==0:        [c0, r0, x0, y0]                -> phi[0]
    //   1..511:      [x_{2q-1}, y_{2q-1}, x_{2q}, y_{2q}] -> phi[2q-1], phi[2q]
    //   q==512:      [x1023, y1023, c1, r1]          -> phi[1023]
    //   513..1024:   row1, k = 2q-2 (flat)           -> phi[k], phi[k+1]
    auto decode = [&](float4 v, int q) {
        if (q == 0) {
            phi[0] = fast_atan2f(v.w - r0, v.z - c0);
        } else if (q < 512) {
            const int k = 2 * q - 1;
            phi[k]     = fast_atan2f(v.y - r0, v.x - c0);
            phi[k + 1] = fast_atan2f(v.w - r0, v.z - c0);
        } else if (q == 512) {
            phi[1023] = fast_atan2f(v.y - r0, v.x - c0);
        } else {
            const int k = 2 * q - 2;
            phi[k]     = fast_atan2f(v.y - r1, v.x - c1);
            phi[k + 1] = fast_atan2f(v.w - r1, v.z - c1);
        }
    };

    // Issue all global loads first (MLP), then decode.
    float4 v[4];
#pragma unroll
    for (int s = 0; s < 4; ++s) v[s] = vp[t + s * BLK];
    float4 vt;
    if (t == 0) vt = vp[1024];
#pragma unroll
    for (int s = 0; s < 4; ++s) decode(v[s], t + s * BLK);
    if (t == 0) decode(vt, 1024);

    __syncthreads();

    // Epilogue: thread t -> row0 floats 4t..4t+3 and row1 floats 4t..4t+3.
    // ds_read_b128 at 16B/lane consecutive = conflict-free.
    const float4* __restrict__ phi4 = (const float4*)phi;
    const float4 p0 = phi4[t];
    const float4 p1 = phi4[t + 256];
    const int jn = (4 * t + 4) & (NVERT - 1);  // wrap j=1023 -> 0
    const float pn0 = phi[jn];
    const float pn1 = phi[NVERT + jn];

    float4 o0, o1;
    o0.x = p0.x - p0.y; o0.y = p0.y - p0.z; o0.z = p0.z - p0.w; o0.w = p0.w - pn0;
    o1.x = p1.x - p1.y; o1.y = p1.y - p1.z; o1.z = p1.z - p1.w; o1.w = p1.w - pn1;

    float4* __restrict__ op = (float4*)(out + (size_t)pb * (2 * NVERT));
    op[t] = o0;        // row0: contiguous 4 KB
    op[t + 256] = o1;  // row1: contiguous 4 KB
}

extern "C" void kernel_launch(void* const* d_in, const int* in_sizes, int n_in,
                              void* d_out, int out_size, void* d_ws, size_t ws_size,
                              hipStream_t stream) {
    const float* x = (const float*)d_in[0];
    float* out = (float*)d_out;
    const int B = in_sizes[0] / ROWSTRIDE;  // 16384
    calweight_kernel<<<B / 2, BLK, 0, stream>>>(x, out);
}